// Round 2
// baseline (151.199 us; speedup 1.0000x reference)
//
#include <hip/hip_runtime.h>
#include <math.h>

#define B_ 32
#define N_ 512
#define F_ 1024
#define EPS 1e-6f

typedef _Float16 h8v __attribute__((ext_vector_type(8)));
typedef _Float16 h4v __attribute__((ext_vector_type(4)));
typedef float    f4v __attribute__((ext_vector_type(4)));

__device__ __forceinline__ void gl_lds16(const void* g, void* l) {
    __builtin_amdgcn_global_load_lds(
        (const __attribute__((address_space(1))) unsigned int*)g,
        (__attribute__((address_space(3))) unsigned int*)l, 16, 0, 0);
}

// ---------------------------------------------------------------------------
// Kernel A (merged): blocks 0..4095 -> per-row sum/sumsq + x->fp16 (one wave
// per row); blocks 4096..4351 -> W->fp16.  (unchanged)
// ---------------------------------------------------------------------------
__global__ __launch_bounds__(256) void prep_kernel(const float* __restrict__ x,
                                                   const float* __restrict__ W,
                                                   float* __restrict__ sq,
                                                   float* __restrict__ s,
                                                   _Float16* __restrict__ xh,
                                                   _Float16* __restrict__ Wh) {
    const int bid = blockIdx.x;
    if (bid < 4096) {
        int row  = bid * 4 + (threadIdx.x >> 6);
        int lane = threadIdx.x & 63;
        const float4* xr = (const float4*)(x + (size_t)row * F_);
        float a1 = 0.f, a2 = 0.f;
#pragma unroll
        for (int it = 0; it < 4; ++it) {
            float4 v = xr[lane + it * 64];
            a1 += v.x + v.y + v.z + v.w;
            a2 += v.x * v.x + v.y * v.y + v.z * v.z + v.w * v.w;
            h4v h;
            h[0] = (_Float16)v.x; h[1] = (_Float16)v.y;
            h[2] = (_Float16)v.z; h[3] = (_Float16)v.w;
            *(h4v*)&xh[(size_t)row * F_ + (size_t)(lane + it * 64) * 4] = h;
        }
#pragma unroll
        for (int off = 32; off > 0; off >>= 1) {
            a1 += __shfl_xor(a1, off);
            a2 += __shfl_xor(a2, off);
        }
        if (lane == 0) { s[row] = a1; sq[row] = a2; }
    } else {
        size_t e = ((size_t)(bid - 4096) * 256 + threadIdx.x) * 4;
        float4 v = *(const float4*)(W + e);
        h4v h;
        h[0] = (_Float16)v.x; h[1] = (_Float16)v.y;
        h[2] = (_Float16)v.z; h[3] = (_Float16)v.w;
        *(h4v*)&Wh[e] = h;
    }
}

// ---------------------------------------------------------------------------
// Kernel B: dist GEMM 256(M)x128(N) tile, BK=64, 8 waves (4M x 2N, 64x64 each),
// 1 block/CU (grid 256 = one residency round). 3-buffer depth-2 pipeline:
// raw s_barrier + counted vmcnt(6) (T4) -- loads stay in flight across
// barriers; no vmcnt(0) drain in the steady-state loop.
// Epilogue: chunk (256-row) column max -> single exp pass (sum + E store).
// pm/pl are now [2][B][N] (2 i-chunks of 256).
// ---------------------------------------------------------------------------
__global__ __launch_bounds__(512) void dist_mfma(const _Float16* __restrict__ xh,
                                                 const float* __restrict__ sq,
                                                 const float* __restrict__ s,
                                                 _Float16* __restrict__ Eb,
                                                 float* __restrict__ pm,
                                                 float* __restrict__ pl) {
    // XCD-bijective swizzle: 256 blocks, 32 logical-consecutive per XCD
    // (= 4 whole batches per XCD).
    const int d       = blockIdx.x;
    const int logical = (d & 7) * 32 + (d >> 3);
    const int b  = logical >> 3;
    const int t5 = logical & 7;
    const int ic = t5 >> 2;          // i-chunk 0..1 (256 rows)
    const int i0 = ic * 256;
    const int j0 = (t5 & 3) * 128;

    __shared__ __align__(16) _Float16 Ab[3][256 * 64];   // 96 KB
    __shared__ __align__(16) _Float16 Bb[3][128 * 64];   // 48 KB
    __shared__ float sm_m[4][128];
    __shared__ float sm_s[4][128];
    __shared__ float sm_c[128];

    const int tid  = threadIdx.x;
    const int lane = tid & 63;
    const int w    = tid >> 6;       // 0..7
    const int wm   = w >> 1;         // 0..3  (64-row group)
    const int wn   = w & 1;          // 0..1  (64-col group)
    const int im   = wm * 64;
    const int jn   = wn * 64;
    const int fr   = lane & 15;
    const int kq   = lane >> 4;      // 0..3
    const int q4   = kq * 4;

    // staging offsets: A 256x64 fp16 = 2048 16B-chunks -> 4/thread;
    //                  B 128x64 = 1024 chunks -> 2/thread.
    size_t aOff[4]; int alo[4];
    size_t bOff[2]; int blo[2];
#pragma unroll
    for (int it = 0; it < 4; ++it) {
        int flat = it * 512 + tid;
        int row  = flat >> 3;
        int c8   = (flat & 7) ^ (row & 7);
        aOff[it] = ((size_t)(b * N_ + i0 + row)) * F_ + c8 * 8;
        alo[it]  = flat * 8;
    }
#pragma unroll
    for (int it = 0; it < 2; ++it) {
        int flat = it * 512 + tid;
        int row  = flat >> 3;
        int c8   = (flat & 7) ^ (row & 7);
        bOff[it] = ((size_t)(b * N_ + j0 + row)) * F_ + c8 * 8;
        blo[it]  = flat * 8;
    }

    f4v acc[4][4] = {};

    _Float16 *A0 = Ab[0], *A1 = Ab[1], *A2 = Ab[2];
    _Float16 *B0 = Bb[0], *B1 = Bb[1], *B2 = Bb[2];

    auto STAGE = [&](int kk, _Float16* Ad, _Float16* Bd) {
#pragma unroll
        for (int it = 0; it < 4; ++it) gl_lds16(xh + aOff[it] + kk, Ad + alo[it]);
#pragma unroll
        for (int it = 0; it < 2; ++it) gl_lds16(xh + bOff[it] + kk, Bd + blo[it]);
    };
    auto COMPUTE = [&](const _Float16* As_, const _Float16* Bs_) {
#pragma unroll
        for (int kf = 0; kf < 2; ++kf) {
            h8v a[4], bb[4];
#pragma unroll
            for (int mi = 0; mi < 4; ++mi) {
                int r = im + mi * 16 + fr;
                a[mi] = *(const h8v*)&As_[r * 64 + (((kf << 2) | kq) ^ (r & 7)) * 8];
            }
#pragma unroll
            for (int ni = 0; ni < 4; ++ni) {
                int r = jn + ni * 16 + fr;
                bb[ni] = *(const h8v*)&Bs_[r * 64 + (((kf << 2) | kq) ^ (r & 7)) * 8];
            }
#pragma unroll
            for (int mi = 0; mi < 4; ++mi)
#pragma unroll
                for (int ni = 0; ni < 4; ++ni)
                    acc[mi][ni] = __builtin_amdgcn_mfma_f32_16x16x32_f16(a[mi], bb[ni], acc[mi][ni], 0, 0, 0);
        }
    };

    const int NT = F_ / 64;          // 16 K-steps
    STAGE(0, A0, B0);                // 6 loads/thread in flight
    STAGE(64, A1, B1);               // 12 in flight
    for (int t = 0; t < NT - 1; ++t) {
        // wait stage(t) (6 of stage(t+1) stay in flight), sync, then prefetch t+2
        asm volatile("s_waitcnt vmcnt(6)" ::: "memory");
        __builtin_amdgcn_s_barrier();
        __builtin_amdgcn_sched_barrier(0);
        if (t + 2 < NT) STAGE((t + 2) * 64, A2, B2);
        COMPUTE(A0, B0);
        _Float16* ta = A0; A0 = A1; A1 = A2; A2 = ta;
        _Float16* tb = B0; B0 = B1; B1 = B2; B2 = tb;
    }
    asm volatile("s_waitcnt vmcnt(0)" ::: "memory");
    __builtin_amdgcn_s_barrier();
    __builtin_amdgcn_sched_barrier(0);
    COMPUTE(A0, B0);

    // epilogue 1: acc -> dist values
    float tjv[4];
#pragma unroll
    for (int ni = 0; ni < 4; ++ni) {
        int j = j0 + jn + ni * 16 + fr;
        tjv[ni] = sq[b * N_ + j] - 2.f * EPS * s[b * N_ + j] + (float)F_ * EPS * EPS;
    }
#pragma unroll
    for (int mi = 0; mi < 4; ++mi)
#pragma unroll
        for (int r = 0; r < 4; ++r) {
            int i = i0 + im + mi * 16 + q4 + r;
            float ti = sq[b * N_ + i] + 2.f * EPS * s[b * N_ + i];
#pragma unroll
            for (int ni = 0; ni < 4; ++ni) {
                int j = j0 + jn + ni * 16 + fr;
                float d2 = ti + tjv[ni] - 2.f * acc[mi][ni][r];
                float dd = (i == j) ? 0.f : sqrtf(fmaxf(d2, 0.f));
                acc[mi][ni][r] = dd;
            }
        }

    // epilogue 2: per-column chunk max (over this block's 256 rows)
#pragma unroll
    for (int ni = 0; ni < 4; ++ni) {
        float m_l = -1e30f;
#pragma unroll
        for (int mi = 0; mi < 4; ++mi)
#pragma unroll
            for (int r = 0; r < 4; ++r) m_l = fmaxf(m_l, acc[mi][ni][r]);
        m_l = fmaxf(m_l, __shfl_xor(m_l, 16));
        m_l = fmaxf(m_l, __shfl_xor(m_l, 32));
        if (lane < 16) sm_m[wm][jn + ni * 16 + lane] = m_l;
    }
    __syncthreads();
    if (tid < 128) {
        float mm = fmaxf(fmaxf(sm_m[0][tid], sm_m[1][tid]),
                         fmaxf(sm_m[2][tid], sm_m[3][tid]));
        pm[((size_t)ic * B_ + b) * N_ + j0 + tid] = mm;
        sm_c[tid] = mm;
    }
    __syncthreads();

    // epilogue 3: single exp pass: E = exp(d - m_chunk), accumulate sum
#pragma unroll
    for (int ni = 0; ni < 4; ++ni) {
        float mc = sm_c[jn + ni * 16 + fr];
        int j = j0 + jn + ni * 16 + fr;
        float s_l = 0.f;
#pragma unroll
        for (int mi = 0; mi < 4; ++mi)
#pragma unroll
            for (int r = 0; r < 4; ++r) {
                float e = __expf(acc[mi][ni][r] - mc);
                s_l += e;
                int i = i0 + im + mi * 16 + q4 + r;
                Eb[((size_t)(b * N_ + i)) * N_ + j] = (_Float16)e;
            }
        s_l += __shfl_xor(s_l, 16);
        s_l += __shfl_xor(s_l, 32);
        if (lane < 16) sm_s[wm][jn + ni * 16 + lane] = s_l;
    }
    __syncthreads();
    if (tid < 128)
        pl[((size_t)ic * B_ + b) * N_ + j0 + tid] =
            (sm_s[0][tid] + sm_s[1][tid]) + (sm_s[2][tid] + sm_s[3][tid]);
}

// ---------------------------------------------------------------------------
// Kernel C: out = (E . alpha_j) @ W^T. 256(i)x128(k) tile, BK=64 over j,
// same 3-buffer counted-vmcnt pipeline, 8 waves, grid 256.
// alpha combine over 2 chunks; alpha folded into W-side fragments as fp16.
// ---------------------------------------------------------------------------
__global__ __launch_bounds__(512) void out_mfma(const _Float16* __restrict__ Eb,
                                                const _Float16* __restrict__ Wh,
                                                const float* __restrict__ pm,
                                                const float* __restrict__ pl,
                                                float* __restrict__ out) {
    const int d       = blockIdx.x;
    const int logical = (d & 7) * 32 + (d >> 3);
    const int b  = logical >> 3;
    const int t5 = logical & 7;
    const int ic = t5 >> 2;          // E's i-chunk (matches dist's 256-row chunk)
    const int i0 = ic * 256;
    const int k0 = (t5 & 3) * 128;

    __shared__ __align__(16) _Float16 Ab[3][256 * 64];
    __shared__ __align__(16) _Float16 Bb[3][128 * 64];
    __shared__ __align__(16) _Float16 af[N_];

    const int tid  = threadIdx.x;
    const int lane = tid & 63;
    const int w    = tid >> 6;
    const int wm   = w >> 1;
    const int wn   = w & 1;
    const int im   = wm * 64;
    const int kn   = wn * 64;
    const int fr   = lane & 15;
    const int kq   = lane >> 4;
    const int fk   = kq * 8;
    const int q4   = kq * 4;

    // alpha table: combine the 2 chunk partials (one j per thread)
    {
        int j = tid;
        float m0 = pm[((size_t)0 * B_ + b) * N_ + j];
        float m1 = pm[((size_t)1 * B_ + b) * N_ + j];
        float mx = fmaxf(m0, m1);
        float l  = pl[((size_t)0 * B_ + b) * N_ + j] * __expf(m0 - mx)
                 + pl[((size_t)1 * B_ + b) * N_ + j] * __expf(m1 - mx);
        float mc = (ic == 0) ? m0 : m1;
        af[j] = (_Float16)(__expf(mc - mx) / l);
    }

    size_t aOff[4]; int alo[4];
    size_t bOff[2]; int blo[2];
#pragma unroll
    for (int it = 0; it < 4; ++it) {
        int flat = it * 512 + tid;
        int row  = flat >> 3;
        int c8   = (flat & 7) ^ (row & 7);
        aOff[it] = ((size_t)(b * N_ + i0 + row)) * N_ + c8 * 8;
        alo[it]  = flat * 8;
    }
#pragma unroll
    for (int it = 0; it < 2; ++it) {
        int flat = it * 512 + tid;
        int row  = flat >> 3;
        int c8   = (flat & 7) ^ (row & 7);
        bOff[it] = ((size_t)(k0 + row)) * N_ + c8 * 8;
        blo[it]  = flat * 8;
    }

    f4v acc[4][4] = {};

    _Float16 *A0 = Ab[0], *A1 = Ab[1], *A2 = Ab[2];
    _Float16 *B0 = Bb[0], *B1 = Bb[1], *B2 = Bb[2];

    auto STAGE = [&](int jj, _Float16* Ad, _Float16* Bd) {
#pragma unroll
        for (int it = 0; it < 4; ++it) gl_lds16(Eb + aOff[it] + jj, Ad + alo[it]);
#pragma unroll
        for (int it = 0; it < 2; ++it) gl_lds16(Wh + bOff[it] + jj, Bd + blo[it]);
    };
    auto COMPUTE = [&](int jj, const _Float16* As_, const _Float16* Bs_) {
#pragma unroll
        for (int kf = 0; kf < 2; ++kf) {
            h8v a[4], bb[4];
            h8v al = *(const h8v*)&af[jj + kf * 32 + fk];
#pragma unroll
            for (int mi = 0; mi < 4; ++mi) {
                int r = im + mi * 16 + fr;
                a[mi] = *(const h8v*)&As_[r * 64 + (((kf << 2) | kq) ^ (r & 7)) * 8];
            }
#pragma unroll
            for (int ni = 0; ni < 4; ++ni) {
                int r = kn + ni * 16 + fr;
                bb[ni] = *(const h8v*)&Bs_[r * 64 + (((kf << 2) | kq) ^ (r & 7)) * 8] * al;
            }
#pragma unroll
            for (int mi = 0; mi < 4; ++mi)
#pragma unroll
                for (int ni = 0; ni < 4; ++ni)
                    acc[mi][ni] = __builtin_amdgcn_mfma_f32_16x16x32_f16(a[mi], bb[ni], acc[mi][ni], 0, 0, 0);
        }
    };

    // fence af writes (full drain is fine here -- before the pipeline starts)
    __syncthreads();

    const int NT = N_ / 64;          // 8 K-steps
    STAGE(0, A0, B0);
    STAGE(64, A1, B1);
    for (int t = 0; t < NT - 1; ++t) {
        asm volatile("s_waitcnt vmcnt(6)" ::: "memory");
        __builtin_amdgcn_s_barrier();
        __builtin_amdgcn_sched_barrier(0);
        if (t + 2 < NT) STAGE((t + 2) * 64, A2, B2);
        COMPUTE(t * 64, A0, B0);
        _Float16* ta = A0; A0 = A1; A1 = A2; A2 = ta;
        _Float16* tb = B0; B0 = B1; B1 = B2; B2 = tb;
    }
    asm volatile("s_waitcnt vmcnt(0)" ::: "memory");
    __builtin_amdgcn_s_barrier();
    __builtin_amdgcn_sched_barrier(0);
    COMPUTE((NT - 1) * 64, A0, B0);

#pragma unroll
    for (int mi = 0; mi < 4; ++mi)
#pragma unroll
        for (int r = 0; r < 4; ++r) {
            int i = i0 + im + mi * 16 + q4 + r;
#pragma unroll
            for (int ni = 0; ni < 4; ++ni) {
                int k = k0 + kn + ni * 16 + fr;
                out[((size_t)(b * N_ + i)) * N_ + k] = acc[mi][ni][r];
            }
        }
}

// ---------------------------------------------------------------------------
extern "C" void kernel_launch(void* const* d_in, const int* in_sizes, int n_in,
                              void* d_out, int out_size, void* d_ws, size_t ws_size,
                              hipStream_t stream) {
    const float* x = (const float*)d_in[0];
    const float* W = (const float*)d_in[1];
    float* out = (float*)d_out;

    const size_t NN  = (size_t)B_ * N_ * N_;       // 8.39M elements
    const size_t NFh = (size_t)B_ * N_ * F_ / 2;   // fp16 x in float slots

    float*    ws = (float*)d_ws;
    _Float16* Eb = (_Float16*)ws;                   // B*N*N fp16
    _Float16* xh = (_Float16*)(ws + NN / 2);        // B*N*F fp16
    _Float16* Wh = (_Float16*)(ws + NN / 2 + NFh);  // N*N fp16
    float*    sq = ws + NN / 2 + NFh + (size_t)N_ * N_ / 2;
    float*    s  = sq + (size_t)B_ * N_;
    float*    pm = s  + (size_t)B_ * N_;            // 2*B*N used
    float*    pl = pm + (size_t)4 * B_ * N_;        // 2*B*N used

    prep_kernel<<<4096 + 256, 256, 0, stream>>>(x, W, sq, s, xh, Wh);
    dist_mfma<<<256, 512, 0, stream>>>(xh, sq, s, Eb, pm, pl);
    out_mfma<<<256, 512, 0, stream>>>(Eb, Wh, pm, pl, out);
}

// Round 3
// 143.037 us; speedup vs baseline: 1.0571x; 1.0571x over previous
//
#include <hip/hip_runtime.h>
#include <math.h>

#define B_ 32
#define N_ 512
#define F_ 1024
#define EPS 1e-6f

typedef _Float16 h8v __attribute__((ext_vector_type(8)));
typedef _Float16 h4v __attribute__((ext_vector_type(4)));
typedef float    f4v __attribute__((ext_vector_type(4)));

__device__ __forceinline__ void gl_lds16(const void* g, void* l) {
    __builtin_amdgcn_global_load_lds(
        (const __attribute__((address_space(1))) unsigned int*)g,
        (__attribute__((address_space(3))) unsigned int*)l, 16, 0, 0);
}

// ---------------------------------------------------------------------------
// Kernel A (merged): blocks 0..4095 -> per-row sum/sumsq + x->fp16 (one wave
// per row); blocks 4096..4351 -> W->fp16.
// ---------------------------------------------------------------------------
__global__ __launch_bounds__(256) void prep_kernel(const float* __restrict__ x,
                                                   const float* __restrict__ W,
                                                   float* __restrict__ sq,
                                                   float* __restrict__ s,
                                                   _Float16* __restrict__ xh,
                                                   _Float16* __restrict__ Wh) {
    const int bid = blockIdx.x;
    if (bid < 4096) {
        int row  = bid * 4 + (threadIdx.x >> 6);
        int lane = threadIdx.x & 63;
        const float4* xr = (const float4*)(x + (size_t)row * F_);
        float a1 = 0.f, a2 = 0.f;
#pragma unroll
        for (int it = 0; it < 4; ++it) {
            float4 v = xr[lane + it * 64];
            a1 += v.x + v.y + v.z + v.w;
            a2 += v.x * v.x + v.y * v.y + v.z * v.z + v.w * v.w;
            h4v h;
            h[0] = (_Float16)v.x; h[1] = (_Float16)v.y;
            h[2] = (_Float16)v.z; h[3] = (_Float16)v.w;
            *(h4v*)&xh[(size_t)row * F_ + (size_t)(lane + it * 64) * 4] = h;
        }
#pragma unroll
        for (int off = 32; off > 0; off >>= 1) {
            a1 += __shfl_xor(a1, off);
            a2 += __shfl_xor(a2, off);
        }
        if (lane == 0) { s[row] = a1; sq[row] = a2; }
    } else {
        size_t e = ((size_t)(bid - 4096) * 256 + threadIdx.x) * 4;
        float4 v = *(const float4*)(W + e);
        h4v h;
        h[0] = (_Float16)v.x; h[1] = (_Float16)v.y;
        h[2] = (_Float16)v.z; h[3] = (_Float16)v.w;
        *(h4v*)&Wh[e] = h;
    }
}

// ---------------------------------------------------------------------------
// Kernel B: dist GEMM 128x128 tile, BK=64, XOR-swizzled LDS, 4 waves,
// double-buffered 1-barrier loop, XCD-bijective batch-grouped swizzle
// (proven R1 structure, 2 blocks/CU). NEW: diagonal-tile dedup -- when
// i0 == j0 the B-panel equals the A-panel, so skip B staging and read
// B-fragments from the A buffer (block-uniform branch).
// Epilogue: chunk max first, then single exp pass (sum + E store).
// Grid: 512 1-D blocks.
// ---------------------------------------------------------------------------
__global__ __launch_bounds__(256) void dist_mfma(const _Float16* __restrict__ xh,
                                                 const float* __restrict__ sq,
                                                 const float* __restrict__ s,
                                                 _Float16* __restrict__ Eb,
                                                 float* __restrict__ pm,
                                                 float* __restrict__ pl) {
    const int d       = blockIdx.x;
    const int logical = (d & 7) * 64 + (d >> 3);
    const int b  = logical >> 4;
    const int t  = logical & 15;
    const int iy = t >> 2;          // i-chunk index (0..3)
    const int i0 = iy * 128;
    const int j0 = (t & 3) * 128;
    const bool diag = (iy == (t & 3));

    __shared__ __align__(16) _Float16 Ah0[128 * 64];
    __shared__ __align__(16) _Float16 Ah1[128 * 64];
    __shared__ __align__(16) _Float16 Bh0[128 * 64];
    __shared__ __align__(16) _Float16 Bh1[128 * 64];
    __shared__ float sm_m[2][128];
    __shared__ float sm_s[2][128];
    __shared__ float sm_c[128];

    const int tid  = threadIdx.x;
    const int lane = tid & 63;
    const int w    = tid >> 6;
    const int im   = (w >> 1) * 64;
    const int jn   = (w & 1) * 64;
    const int fr   = lane & 15;
    const int kq   = lane >> 4;      // 0..3
    const int q4   = kq * 4;

    // staging addresses (swizzled global source -> contiguous LDS dest)
    size_t aOff[4], bOff[4];
    int    lOff[4];
#pragma unroll
    for (int it = 0; it < 4; ++it) {
        int flat = it * 256 + tid;       // chunk id: tile = 128 rows x 8 chunks
        int row  = flat >> 3;
        int c8   = (flat & 7) ^ (row & 7);
        aOff[it] = ((size_t)(b * N_ + i0 + row)) * F_ + c8 * 8;
        bOff[it] = ((size_t)(b * N_ + j0 + row)) * F_ + c8 * 8;
        lOff[it] = flat * 8;
    }

    f4v acc[4][4] = {};

    auto STAGE = [&](int k0, _Float16* Ad, _Float16* Bd) {
#pragma unroll
        for (int it = 0; it < 4; ++it)
            gl_lds16(xh + aOff[it] + k0, Ad + lOff[it]);
        if (!diag) {
#pragma unroll
            for (int it = 0; it < 4; ++it)
                gl_lds16(xh + bOff[it] + k0, Bd + lOff[it]);
        }
    };
    auto COMPUTE = [&](const _Float16* As_, const _Float16* Bs_) {
        const _Float16* Bsel = diag ? As_ : Bs_;
#pragma unroll
        for (int kf = 0; kf < 2; ++kf) {
            h8v a[4], bb[4];
#pragma unroll
            for (int mi = 0; mi < 4; ++mi) {
                int r = im + mi * 16 + fr;
                a[mi] = *(const h8v*)&As_[r * 64 + (((kf << 2) | kq) ^ (r & 7)) * 8];
            }
#pragma unroll
            for (int ni = 0; ni < 4; ++ni) {
                int r = jn + ni * 16 + fr;
                bb[ni] = *(const h8v*)&Bsel[r * 64 + (((kf << 2) | kq) ^ (r & 7)) * 8];
            }
#pragma unroll
            for (int mi = 0; mi < 4; ++mi)
#pragma unroll
                for (int ni = 0; ni < 4; ++ni)
                    acc[mi][ni] = __builtin_amdgcn_mfma_f32_16x16x32_f16(a[mi], bb[ni], acc[mi][ni], 0, 0, 0);
        }
    };

    // 16 K-tiles, double-buffered: stage t+1 before computing t.
    STAGE(0, Ah0, Bh0);
    __syncthreads();
    for (int p = 0; p < 7; ++p) {
        STAGE((2 * p + 1) * 64, Ah1, Bh1);
        COMPUTE(Ah0, Bh0);
        __syncthreads();
        STAGE((2 * p + 2) * 64, Ah0, Bh0);
        COMPUTE(Ah1, Bh1);
        __syncthreads();
    }
    STAGE(15 * 64, Ah1, Bh1);
    COMPUTE(Ah0, Bh0);
    __syncthreads();
    COMPUTE(Ah1, Bh1);

    // epilogue 1: acc -> dist values
    float tjv[4];
#pragma unroll
    for (int ni = 0; ni < 4; ++ni) {
        int j = j0 + jn + ni * 16 + fr;
        tjv[ni] = sq[b * N_ + j] - 2.f * EPS * s[b * N_ + j] + (float)F_ * EPS * EPS;
    }
#pragma unroll
    for (int mi = 0; mi < 4; ++mi)
#pragma unroll
        for (int r = 0; r < 4; ++r) {
            int i = i0 + im + mi * 16 + q4 + r;
            float ti = sq[b * N_ + i] + 2.f * EPS * s[b * N_ + i];
#pragma unroll
            for (int ni = 0; ni < 4; ++ni) {
                int j = j0 + jn + ni * 16 + fr;
                float d2 = ti + tjv[ni] - 2.f * acc[mi][ni][r];
                float dd = (i == j) ? 0.f : sqrtf(fmaxf(d2, 0.f));
                acc[mi][ni][r] = dd;
            }
        }

    // epilogue 2: per-column chunk max (max-only reduction)
#pragma unroll
    for (int ni = 0; ni < 4; ++ni) {
        float m_l = -1e30f;
#pragma unroll
        for (int mi = 0; mi < 4; ++mi)
#pragma unroll
            for (int r = 0; r < 4; ++r) m_l = fmaxf(m_l, acc[mi][ni][r]);
        m_l = fmaxf(m_l, __shfl_xor(m_l, 16));
        m_l = fmaxf(m_l, __shfl_xor(m_l, 32));
        if (lane < 16) sm_m[w >> 1][jn + ni * 16 + lane] = m_l;
    }
    __syncthreads();
    if (tid < 128) {
        float mm = fmaxf(sm_m[0][tid], sm_m[1][tid]);
        pm[((size_t)iy * B_ + b) * N_ + j0 + tid] = mm;
        sm_c[tid] = mm;
    }
    __syncthreads();

    // epilogue 3: single exp pass: E = exp(d - m_chunk), accumulate sum
#pragma unroll
    for (int ni = 0; ni < 4; ++ni) {
        float mc = sm_c[jn + ni * 16 + fr];
        int j = j0 + jn + ni * 16 + fr;
        float s_l = 0.f;
#pragma unroll
        for (int mi = 0; mi < 4; ++mi)
#pragma unroll
            for (int r = 0; r < 4; ++r) {
                float e = __expf(acc[mi][ni][r] - mc);
                s_l += e;
                int i = i0 + im + mi * 16 + q4 + r;
                Eb[((size_t)(b * N_ + i)) * N_ + j] = (_Float16)e;
            }
        s_l += __shfl_xor(s_l, 16);
        s_l += __shfl_xor(s_l, 32);
        if (lane < 16) sm_s[w >> 1][jn + ni * 16 + lane] = s_l;
    }
    __syncthreads();
    if (tid < 128)
        pl[((size_t)iy * B_ + b) * N_ + j0 + tid] = sm_s[0][tid] + sm_s[1][tid];
}

// ---------------------------------------------------------------------------
// Kernel C: out = (E . alpha_j) @ W^T. 128x128 tile, BK=64, swizzled LDS,
// double-buffered prefetch + XCD-bijective batch-grouped swizzle.
// Grid: 512 1-D blocks.  (proven R1 structure, unchanged)
// ---------------------------------------------------------------------------
__global__ __launch_bounds__(256) void out_mfma(const _Float16* __restrict__ Eb,
                                                const _Float16* __restrict__ Wh,
                                                const float* __restrict__ pm,
                                                const float* __restrict__ pl,
                                                float* __restrict__ out) {
    const int d       = blockIdx.x;
    const int logical = (d & 7) * 64 + (d >> 3);
    const int b  = logical >> 4;
    const int t  = logical & 15;
    const int ic = t >> 2;          // E's i-chunk
    const int i0 = ic * 128;
    const int k0 = (t & 3) * 128;

    __shared__ __align__(16) _Float16 As0[128 * 64];
    __shared__ __align__(16) _Float16 As1[128 * 64];
    __shared__ __align__(16) _Float16 Bs0[128 * 64];
    __shared__ __align__(16) _Float16 Bs1[128 * 64];
    __shared__ __align__(16) _Float16 af[N_];

    const int tid  = threadIdx.x;
    const int lane = tid & 63;
    const int w    = tid >> 6;
    const int im   = (w >> 1) * 64;
    const int kn   = (w & 1) * 64;
    const int fr   = lane & 15;
    const int kq   = lane >> 4;
    const int fk   = kq * 8;
    const int q4   = kq * 4;

    // alpha table (512 j, 2 per thread)
    for (int j = tid; j < N_; j += 256) {
        float mx = -1e30f;
#pragma unroll
        for (int c = 0; c < 4; ++c) mx = fmaxf(mx, pm[((size_t)c * B_ + b) * N_ + j]);
        float l = 0.f;
#pragma unroll
        for (int c = 0; c < 4; ++c)
            l += pl[((size_t)c * B_ + b) * N_ + j] * __expf(pm[((size_t)c * B_ + b) * N_ + j] - mx);
        af[j] = (_Float16)(__expf(pm[((size_t)ic * B_ + b) * N_ + j] - mx) / l);
    }

    size_t aOff[4], bOff[4];
    int    lOff[4];
#pragma unroll
    for (int it = 0; it < 4; ++it) {
        int flat = it * 256 + tid;
        int row  = flat >> 3;
        int c8   = (flat & 7) ^ (row & 7);
        aOff[it] = ((size_t)(b * N_ + i0 + row)) * N_ + c8 * 8;
        bOff[it] = ((size_t)(k0 + row)) * N_ + c8 * 8;
        lOff[it] = flat * 8;
    }

    f4v acc[4][4] = {};

    auto STAGE = [&](int jj, _Float16* Ad, _Float16* Bd) {
#pragma unroll
        for (int it = 0; it < 4; ++it) {
            gl_lds16(Eb + aOff[it] + jj, Ad + lOff[it]);
            gl_lds16(Wh + bOff[it] + jj, Bd + lOff[it]);
        }
    };
    auto COMPUTE = [&](int jj, const _Float16* As_, const _Float16* Bs_) {
#pragma unroll
        for (int kf = 0; kf < 2; ++kf) {
            h8v a[4], bb[4];
            h8v al = *(const h8v*)&af[jj + kf * 32 + fk];
#pragma unroll
            for (int mi = 0; mi < 4; ++mi) {
                int r = im + mi * 16 + fr;
                a[mi] = *(const h8v*)&As_[r * 64 + (((kf << 2) | kq) ^ (r & 7)) * 8];
            }
#pragma unroll
            for (int ni = 0; ni < 4; ++ni) {
                int r = kn + ni * 16 + fr;
                bb[ni] = *(const h8v*)&Bs_[r * 64 + (((kf << 2) | kq) ^ (r & 7)) * 8] * al;
            }
#pragma unroll
            for (int mi = 0; mi < 4; ++mi)
#pragma unroll
                for (int ni = 0; ni < 4; ++ni)
                    acc[mi][ni] = __builtin_amdgcn_mfma_f32_16x16x32_f16(a[mi], bb[ni], acc[mi][ni], 0, 0, 0);
        }
    };

    // 8 K-tiles (contraction over j), double-buffered.
    STAGE(0, As0, Bs0);
    __syncthreads();   // also fences the af writes
    for (int p = 0; p < 3; ++p) {
        STAGE((2 * p + 1) * 64, As1, Bs1);
        COMPUTE((2 * p) * 64, As0, Bs0);
        __syncthreads();
        STAGE((2 * p + 2) * 64, As0, Bs0);
        COMPUTE((2 * p + 1) * 64, As1, Bs1);
        __syncthreads();
    }
    STAGE(7 * 64, As1, Bs1);
    COMPUTE(6 * 64, As0, Bs0);
    __syncthreads();
    COMPUTE(7 * 64, As1, Bs1);

#pragma unroll
    for (int mi = 0; mi < 4; ++mi)
#pragma unroll
        for (int r = 0; r < 4; ++r) {
            int i = i0 + im + mi * 16 + q4 + r;
#pragma unroll
            for (int ni = 0; ni < 4; ++ni) {
                int k = k0 + kn + ni * 16 + fr;
                out[((size_t)(b * N_ + i)) * N_ + k] = acc[mi][ni][r];
            }
        }
}

// ---------------------------------------------------------------------------
extern "C" void kernel_launch(void* const* d_in, const int* in_sizes, int n_in,
                              void* d_out, int out_size, void* d_ws, size_t ws_size,
                              hipStream_t stream) {
    const float* x = (const float*)d_in[0];
    const float* W = (const float*)d_in[1];
    float* out = (float*)d_out;

    const size_t NN  = (size_t)B_ * N_ * N_;       // 8.39M elements
    const size_t NFh = (size_t)B_ * N_ * F_ / 2;   // fp16 x in float slots

    float*    ws = (float*)d_ws;
    _Float16* Eb = (_Float16*)ws;                   // B*N*N fp16
    _Float16* xh = (_Float16*)(ws + NN / 2);        // B*N*F fp16
    _Float16* Wh = (_Float16*)(ws + NN / 2 + NFh);  // N*N fp16
    float*    sq = ws + NN / 2 + NFh + (size_t)N_ * N_ / 2;
    float*    s  = sq + (size_t)B_ * N_;
    float*    pm = s  + (size_t)B_ * N_;            // 4*B*N
    float*    pl = pm + (size_t)4 * B_ * N_;        // 4*B*N

    prep_kernel<<<4096 + 256, 256, 0, stream>>>(x, W, sq, s, xh, Wh);
    dist_mfma<<<512, 256, 0, stream>>>(xh, sq, s, Eb, pm, pl);
    out_mfma<<<512, 256, 0, stream>>>(Eb, Wh, pm, pl, out);
}